// Round 1
// baseline (208.917 us; speedup 1.0000x reference)
//
#include <hip/hip_runtime.h>
#include <hip/hip_bf16.h>
#include <stdint.h>

typedef __bf16 bf16_t;
typedef __bf16 bf16x4 __attribute__((ext_vector_type(4)));
typedef __bf16 bf16x8 __attribute__((ext_vector_type(8)));
typedef float  f32x4  __attribute__((ext_vector_type(4)));

// async global -> LDS, 16B per lane. LDS dest must be wave-uniform base (lane*16 implicit).
__device__ __forceinline__ void gload_lds16(const void* g, void* l) {
  __builtin_amdgcn_global_load_lds(
      (__attribute__((address_space(1))) void*)g,
      (__attribute__((address_space(3))) void*)l, 16, 0, 0);
}

// ---------------- f32 -> bf16 cast, 4 elems/thread, grid-stride ----------------
__global__ void cast_kernel(const float* __restrict__ in, bf16_t* __restrict__ out, int n4) {
  const int stride = gridDim.x * blockDim.x;
  for (int i = blockIdx.x * blockDim.x + threadIdx.x; i < n4; i += stride) {
    f32x4 v = reinterpret_cast<const f32x4*>(in)[i];
    bf16x4 o;
    o[0] = (bf16_t)v[0]; o[1] = (bf16_t)v[1]; o[2] = (bf16_t)v[2]; o[3] = (bf16_t)v[3];
    reinterpret_cast<bf16x4*>(out)[i] = o;
  }
}

// ---------------- shared MFMA GEMM: C[m,n] = sum_k A[m,k] * B[n,k] ----------------
// A: M x K row-major bf16, B: N x K row-major bf16 (B-transposed GEMM).
// 128x128 tile, BK=64, 4 waves (2x2 of 64x64), 16x16x32 bf16 MFMA.
// EPI 0: outb[m,n] = bf16( relu(acc + bias[n]) * mask[m] )       (GEMM1 -> h)
// EPI 1: outf[m,n] = acc + Padd[(m>>7)*N + n]                    (GEMM2 -> out_enc)
// EPI 2: outf[m,n] = acc + bias[n]                               (P-GEMM)
template<int EPI>
__global__ __launch_bounds__(256) void gemm_bt(
    const bf16_t* __restrict__ A, const bf16_t* __restrict__ B,
    const int K, const int N,
    const float* __restrict__ bias,
    const float* __restrict__ mask,
    const float* __restrict__ Padd,
    bf16_t* __restrict__ outb,
    float* __restrict__ outf)
{
  __shared__ __align__(16) bf16_t As[128 * 64];
  __shared__ __align__(16) bf16_t Bs[128 * 64];

  const int tid  = threadIdx.x;
  const int lane = tid & 63;
  const int w    = tid >> 6;       // wave 0..3
  const int wm   = w >> 1;         // wave row (0..1)
  const int wn   = w & 1;          // wave col (0..1)
  const long bm  = (long)blockIdx.x * 128;
  const long bn  = (long)blockIdx.y * 128;

  f32x4 acc[4][4] = {};

  // staging: each wave loads 32 rows (4 x 8-row wave-loads) of each tile
  const int srow = w * 32 + (lane >> 3);       // row within tile for this lane
  const int scol = (lane & 7) * 8;             // k-offset (elems) for this lane
  const bf16_t* Abase = A + (bm + srow) * (long)K + scol;
  const bf16_t* Bbase = B + (bn + srow) * (long)K + scol;

  for (int kt = 0; kt < K; kt += 64) {
    #pragma unroll
    for (int it = 0; it < 4; ++it) {
      gload_lds16(Abase + (long)it * 8 * K + kt, &As[(w * 32 + it * 8) * 64]);
      gload_lds16(Bbase + (long)it * 8 * K + kt, &Bs[(w * 32 + it * 8) * 64]);
    }
    asm volatile("s_waitcnt vmcnt(0)" ::: "memory");
    __syncthreads();

    #pragma unroll
    for (int kk = 0; kk < 2; ++kk) {
      const int kof = kk * 32 + (lane >> 4) * 8;
      bf16x8 af[4], bfr[4];
      #pragma unroll
      for (int i = 0; i < 4; ++i)
        af[i] = *reinterpret_cast<const bf16x8*>(&As[(wm * 64 + i * 16 + (lane & 15)) * 64 + kof]);
      #pragma unroll
      for (int j = 0; j < 4; ++j)
        bfr[j] = *reinterpret_cast<const bf16x8*>(&Bs[(wn * 64 + j * 16 + (lane & 15)) * 64 + kof]);
      #pragma unroll
      for (int i = 0; i < 4; ++i)
        #pragma unroll
        for (int j = 0; j < 4; ++j)
          acc[i][j] = __builtin_amdgcn_mfma_f32_16x16x32_bf16(af[i], bfr[j], acc[i][j], 0, 0, 0);
    }
    __syncthreads();
  }

  // epilogue: D mapping col = lane&15, row = (lane>>4)*4 + r  [m89-verified]
  #pragma unroll
  for (int j = 0; j < 4; ++j) {
    const long gc = bn + wn * 64 + j * 16 + (lane & 15);
    float bval = 0.f, pval = 0.f;
    if (EPI == 0 || EPI == 2) bval = bias[gc];
    if (EPI == 1)             pval = Padd[(bm >> 7) * (long)N + gc];
    #pragma unroll
    for (int i = 0; i < 4; ++i) {
      const long gr0 = bm + wm * 64 + i * 16 + ((lane >> 4) << 2);
      #pragma unroll
      for (int r = 0; r < 4; ++r) {
        const long gr = gr0 + r;
        const float vsum = acc[i][j][r];
        if (EPI == 0) {
          float hv = vsum + bval;
          hv = hv > 0.f ? hv : 0.f;
          hv *= mask[gr];
          outb[gr * (long)N + gc] = (bf16_t)hv;
        } else if (EPI == 1) {
          outf[gr * (long)N + gc] = vsum + pval;
        } else {
          outf[gr * (long)N + gc] = vsum + bval;
        }
      }
    }
  }
}

// ------------- chunk-local in-place cumsum over 128 rows + chunk partial sums -------------
// h: [32768][512] bf16; thread owns (chunk, 4 consecutive o). 256 chunks of 128 rows.
__global__ void cumsum_local(bf16_t* __restrict__ h, float* __restrict__ partials) {
  const int idx   = blockIdx.x * blockDim.x + threadIdx.x;  // 0..32767
  const int chunk = idx >> 7;                               // 0..255
  const int q     = idx & 127;                              // o-quad
  bf16_t* p = h + (size_t)chunk * (128 * 512) + q * 4;
  float a0 = 0.f, a1 = 0.f, a2 = 0.f, a3 = 0.f;
  #pragma unroll 4
  for (int s = 0; s < 128; ++s) {
    bf16x4 v = *reinterpret_cast<bf16x4*>(p);
    a0 += (float)v[0]; a1 += (float)v[1]; a2 += (float)v[2]; a3 += (float)v[3];
    bf16x4 o;
    o[0] = (bf16_t)a0; o[1] = (bf16_t)a1; o[2] = (bf16_t)a2; o[3] = (bf16_t)a3;
    *reinterpret_cast<bf16x4*>(p) = o;
    p += 512;
  }
  f32x4 pt; pt[0] = a0; pt[1] = a1; pt[2] = a2; pt[3] = a3;
  reinterpret_cast<f32x4*>(partials)[(size_t)chunk * 128 + q] = pt;
}

// ------------- exclusive scan over 32 chunks per (b, o); writes v (f32) -------------
__global__ void scan_chunks(const float* __restrict__ partials, bf16_t* __restrict__ prefixb,
                            float* __restrict__ v_out) {
  const int idx = blockIdx.x * blockDim.x + threadIdx.x;  // 0..4095
  const int b = idx >> 9;
  const int o = idx & 511;
  float run = 0.f;
  #pragma unroll
  for (int c = 0; c < 32; ++c) {
    const size_t off = ((size_t)(b * 32 + c)) * 512 + o;
    prefixb[off] = (bf16_t)run;      // exclusive prefix, bf16 (feeds P-GEMM)
    run += partials[off];
  }
  v_out[idx] = run;                  // v[b][o], f32
}

extern "C" void kernel_launch(void* const* d_in, const int* in_sizes, int n_in,
                              void* d_out, int out_size, void* d_ws, size_t ws_size,
                              hipStream_t stream) {
  const float* x     = (const float*)d_in[0];   // (8,4096,1024)
  const float* mask  = (const float*)d_in[1];   // (8,4096)
  const float* W_enc = (const float*)d_in[2];   // (512,1024)
  const float* b_enc = (const float*)d_in[3];   // (512,)
  const float* W_dec = (const float*)d_in[4];   // (1024,512)
  const float* b_dec = (const float*)d_in[5];   // (1024,)

  float* out     = (float*)d_out;
  float* v_out   = out;            // 8*512
  float* out_enc = out + 4096;     // 8*4096*1024

  char* ws = (char*)d_ws;
  bf16_t* xb       = (bf16_t*)ws;  ws += (size_t)32768 * 1024 * 2;  // 67 MB
  bf16_t* Web      = (bf16_t*)ws;  ws += (size_t)512 * 1024 * 2;    // 1 MB
  bf16_t* Wdb      = (bf16_t*)ws;  ws += (size_t)1024 * 512 * 2;    // 1 MB
  bf16_t* h        = (bf16_t*)ws;  ws += (size_t)32768 * 512 * 2;   // 33.5 MB
  float*  partials = (float*)ws;   ws += (size_t)256 * 512 * 4;     // 512 KB
  bf16_t* prefixb  = (bf16_t*)ws;  ws += (size_t)256 * 512 * 2;     // 256 KB
  float*  P        = (float*)ws;   ws += (size_t)256 * 1024 * 4;    // 1 MB

  // 1) casts
  cast_kernel<<<2048, 256, 0, stream>>>(x, xb, 33554432 / 4);
  cast_kernel<<<256, 256, 0, stream>>>(W_enc, Web, 524288 / 4);
  cast_kernel<<<256, 256, 0, stream>>>(W_dec, Wdb, 524288 / 4);

  // 2) GEMM1: h = relu(x @ W_enc^T + b_enc) * mask   [M=32768, N=512, K=1024]
  gemm_bt<0><<<dim3(256, 4), 256, 0, stream>>>(xb, Web, 1024, 512,
                                               b_enc, mask, nullptr, h, nullptr);

  // 3) chunk-local cumsum (in place) + per-chunk sums
  cumsum_local<<<128, 256, 0, stream>>>(h, partials);

  // 4) scan chunk sums -> exclusive prefixes (bf16) and v (f32, output 0)
  scan_chunks<<<16, 256, 0, stream>>>(partials, prefixb, v_out);

  // 5) P[r,d] = prefix[r,:] @ W_dec[d,:] + b_dec[d]   [M=256, N=1024, K=512]
  gemm_bt<2><<<dim3(2, 8), 256, 0, stream>>>(prefixb, Wdb, 512, 1024,
                                             b_dec, nullptr, nullptr, nullptr, P);

  // 6) GEMM2: out_enc = h_local @ W_dec^T + P[chunk]  [M=32768, N=1024, K=512]
  gemm_bt<1><<<dim3(256, 8), 256, 0, stream>>>(h, Wdb, 512, 1024,
                                               nullptr, nullptr, P, nullptr, out_enc);
}

// Round 2
// 165.234 us; speedup vs baseline: 1.2644x; 1.2644x over previous
//
#include <hip/hip_runtime.h>
#include <hip/hip_bf16.h>
#include <stdint.h>

typedef __bf16 bf16_t;
typedef __bf16 bf16x4 __attribute__((ext_vector_type(4)));
typedef __bf16 bf16x8 __attribute__((ext_vector_type(8)));
typedef float  f32x4  __attribute__((ext_vector_type(4)));

// async global -> LDS, 16B per lane. LDS dest is wave-uniform base + lane*16.
__device__ __forceinline__ void gload_lds16(const void* g, void* l) {
  __builtin_amdgcn_global_load_lds(
      (__attribute__((address_space(1))) void*)g,
      (__attribute__((address_space(3))) void*)l, 16, 0, 0);
}

// ---------------- weights cast: W_enc and W_dec in one launch ----------------
__global__ void cast_weights(const float* __restrict__ a, bf16_t* __restrict__ oa,
                             const float* __restrict__ b, bf16_t* __restrict__ ob,
                             int n4each) {
  const int i = blockIdx.x * blockDim.x + threadIdx.x;  // 0 .. 2*n4each-1 exactly
  const float* src;
  bf16_t* dst;
  int k;
  if (i < n4each) { src = a; dst = oa; k = i; }
  else            { src = b; dst = ob; k = i - n4each; }
  f32x4 v = reinterpret_cast<const f32x4*>(src)[k];
  bf16x4 o;
  o[0] = (bf16_t)v[0]; o[1] = (bf16_t)v[1]; o[2] = (bf16_t)v[2]; o[3] = (bf16_t)v[3];
  reinterpret_cast<bf16x4*>(dst)[k] = o;
}

// ================= GEMM1 fused: h_cum = cumsum128(relu(x@W_enc^T + b)*mask) ==============
// M=32768 (grid.x=256), N=512 (grid.y=4), K=1024. 128x128 tile, 4 waves, BK=64, dbuf.
// A staged from f32 x via registers (fused cast); B via global_load_lds.
// Epilogue: relu+bias+mask -> LDS f32 tile (aliases staging bufs) -> in-block column
// cumsum over the 128-row chunk -> h (bf16) + per-chunk partials (f32).
__global__ __launch_bounds__(256) void gemm1_fused(
    const float* __restrict__ x, const bf16_t* __restrict__ Wenc,
    const float* __restrict__ b_enc, const float* __restrict__ mask,
    bf16_t* __restrict__ h, float* __restrict__ partials)
{
  __shared__ __align__(16) char smem[65536];
  bf16_t* As0 = (bf16_t*)(smem);
  bf16_t* As1 = (bf16_t*)(smem + 16384);
  bf16_t* Bs0 = (bf16_t*)(smem + 32768);
  bf16_t* Bs1 = (bf16_t*)(smem + 49152);
  float*  tile = (float*)smem;  // 128*128 f32, valid only after K-loop

  const int tid  = threadIdx.x;
  const int lane = tid & 63;
  const int w    = tid >> 6;
  const int wm   = w >> 1, wn = w & 1;
  const long bm  = (long)blockIdx.x * 128;
  const long bn  = (long)blockIdx.y * 128;

  f32x4 acc[4][4] = {};

  // B staging (gload_lds): wave w covers rows w*32+it*8+(lane>>3), cols (lane&7)*8..+7
  const int srow = w * 32 + (lane >> 3);
  const int scol = (lane & 7) * 8;
  const bf16_t* Bbase = Wenc + (bn + srow) * 1024 + scol;

  // A reg staging: thread covers rows {p*32 + (tid>>3)}, cols (tid&7)*8..+7 (f32)
  const int ar0 = tid >> 3;
  const int ac0 = (tid & 7) * 8;
  const float* Abase = x + (bm + ar0) * 1024 + ac0;

  f32x4 av[4][2];

  auto aload = [&](int kt) {
    #pragma unroll
    for (int p = 0; p < 4; ++p) {
      const float* s = Abase + (long)p * 32 * 1024 + kt;
      av[p][0] = *reinterpret_cast<const f32x4*>(s);
      av[p][1] = *reinterpret_cast<const f32x4*>(s + 4);
    }
  };
  auto awrite = [&](bf16_t* As) {
    #pragma unroll
    for (int p = 0; p < 4; ++p) {
      bf16x8 o;
      #pragma unroll
      for (int e = 0; e < 4; ++e) {
        o[e]     = (bf16_t)av[p][0][e];
        o[e + 4] = (bf16_t)av[p][1][e];
      }
      *reinterpret_cast<bf16x8*>(&As[(p * 32 + ar0) * 64 + ac0]) = o;
    }
  };
  auto bstage = [&](bf16_t* Bs, int kt) {
    #pragma unroll
    for (int it = 0; it < 4; ++it)
      gload_lds16(Bbase + (long)it * 8 * 1024 + kt, &Bs[(w * 32 + it * 8) * 64]);
  };
  auto mfma_tile = [&](const bf16_t* As, const bf16_t* Bs) {
    #pragma unroll
    for (int kk = 0; kk < 2; ++kk) {
      const int kof = kk * 32 + (lane >> 4) * 8;
      bf16x8 afr[4], bfr[4];
      #pragma unroll
      for (int i = 0; i < 4; ++i)
        afr[i] = *reinterpret_cast<const bf16x8*>(&As[(wm * 64 + i * 16 + (lane & 15)) * 64 + kof]);
      #pragma unroll
      for (int j = 0; j < 4; ++j)
        bfr[j] = *reinterpret_cast<const bf16x8*>(&Bs[(wn * 64 + j * 16 + (lane & 15)) * 64 + kof]);
      #pragma unroll
      for (int i = 0; i < 4; ++i)
        #pragma unroll
        for (int j = 0; j < 4; ++j)
          acc[i][j] = __builtin_amdgcn_mfma_f32_16x16x32_bf16(afr[i], bfr[j], acc[i][j], 0, 0, 0);
    }
  };

  // prologue: fill buffer 0 for kt=0
  aload(0);
  awrite(As0);
  bstage(Bs0, 0);
  __syncthreads();

  // main loop: 16 K-tiles as 8 pairs; compute buf0 / stage buf1, then swap. 1 barrier/step.
  int kt = 64;
  for (int p2 = 0; p2 < 8; ++p2) {
    if (kt < 1024) { aload(kt); bstage(Bs1, kt); }
    mfma_tile(As0, Bs0);
    if (kt < 1024) awrite(As1);
    __syncthreads();
    kt += 64;

    if (kt < 1024) { aload(kt); bstage(Bs0, kt); }
    mfma_tile(As1, Bs1);
    if (kt < 1024) awrite(As0);
    __syncthreads();
    kt += 64;
  }

  // ---- epilogue: relu+bias+mask into f32 tile (aliases staging LDS) ----
  float bv[4];
  #pragma unroll
  for (int j = 0; j < 4; ++j)
    bv[j] = b_enc[bn + wn * 64 + j * 16 + (lane & 15)];

  #pragma unroll
  for (int i = 0; i < 4; ++i) {
    const int rbase = wm * 64 + i * 16 + ((lane >> 4) << 2);
    const f32x4 mv = *reinterpret_cast<const f32x4*>(&mask[bm + rbase]);
    #pragma unroll
    for (int j = 0; j < 4; ++j) {
      const int colj = wn * 64 + j * 16 + (lane & 15);
      #pragma unroll
      for (int r = 0; r < 4; ++r) {
        const int row = rbase + r;
        float hv = acc[i][j][r] + bv[j];
        hv = hv > 0.f ? hv : 0.f;
        hv *= mv[r];
        tile[row * 128 + (colj ^ (((row >> 2) & 1) << 4))] = hv;
      }
    }
  }
  __syncthreads();

  // ---- in-block column cumsum over the 128-row chunk ----
  if (tid < 128) {
    float run = 0.f;
    bf16_t* hp = h + bm * 512 + bn + tid;
    #pragma unroll 4
    for (int s = 0; s < 128; ++s) {
      run += tile[s * 128 + (tid ^ (((s >> 2) & 1) << 4))];
      hp[(long)s * 512] = (bf16_t)run;
    }
    partials[blockIdx.x * 512 + bn + tid] = run;
  }
}

// ================= generic B^T GEMM (bf16 MFMA, dbuf, f32 out) ==================
// EPI 1: outf[m,n] = acc + Padd[(m>>7)*N + n]   (GEMM2)
// EPI 2: outf[m,n] = acc + bias[n]              (P-GEMM)
template<int EPI>
__global__ __launch_bounds__(256) void gemm_bt(
    const bf16_t* __restrict__ A, const bf16_t* __restrict__ B,
    const int K, const int N,
    const float* __restrict__ bias,
    const float* __restrict__ Padd,
    float* __restrict__ outf)
{
  __shared__ __align__(16) bf16_t As[2][128 * 64];
  __shared__ __align__(16) bf16_t Bs[2][128 * 64];

  const int tid  = threadIdx.x;
  const int lane = tid & 63;
  const int w    = tid >> 6;
  const int wm   = w >> 1, wn = w & 1;
  const long bm  = (long)blockIdx.x * 128;
  const long bn  = (long)blockIdx.y * 128;

  f32x4 acc[4][4] = {};

  const int srow = w * 32 + (lane >> 3);
  const int scol = (lane & 7) * 8;
  const bf16_t* Abase = A + (bm + srow) * (long)K + scol;
  const bf16_t* Bbase = B + (bn + srow) * (long)K + scol;

  auto stageA = [&](bf16_t* dst, int kt) {
    #pragma unroll
    for (int it = 0; it < 4; ++it)
      gload_lds16(Abase + (long)it * 8 * K + kt, &dst[(w * 32 + it * 8) * 64]);
  };
  auto stageB = [&](bf16_t* dst, int kt) {
    #pragma unroll
    for (int it = 0; it < 4; ++it)
      gload_lds16(Bbase + (long)it * 8 * K + kt, &dst[(w * 32 + it * 8) * 64]);
  };
  auto mfma_tile = [&](const bf16_t* Asb, const bf16_t* Bsb) {
    #pragma unroll
    for (int kk = 0; kk < 2; ++kk) {
      const int kof = kk * 32 + (lane >> 4) * 8;
      bf16x8 afr[4], bfr[4];
      #pragma unroll
      for (int i = 0; i < 4; ++i)
        afr[i] = *reinterpret_cast<const bf16x8*>(&Asb[(wm * 64 + i * 16 + (lane & 15)) * 64 + kof]);
      #pragma unroll
      for (int j = 0; j < 4; ++j)
        bfr[j] = *reinterpret_cast<const bf16x8*>(&Bsb[(wn * 64 + j * 16 + (lane & 15)) * 64 + kof]);
      #pragma unroll
      for (int i = 0; i < 4; ++i)
        #pragma unroll
        for (int j = 0; j < 4; ++j)
          acc[i][j] = __builtin_amdgcn_mfma_f32_16x16x32_bf16(afr[i], bfr[j], acc[i][j], 0, 0, 0);
    }
  };

  stageA(As[0], 0);
  stageB(Bs[0], 0);
  __syncthreads();

  int kt = 64;
  const int NP = K >> 7;  // K/128 pairs (K multiple of 128)
  for (int p2 = 0; p2 < NP; ++p2) {
    if (kt < K) { stageA(As[1], kt); stageB(Bs[1], kt); }
    mfma_tile(As[0], Bs[0]);
    __syncthreads();
    kt += 64;

    if (kt < K) { stageA(As[0], kt); stageB(Bs[0], kt); }
    mfma_tile(As[1], Bs[1]);
    __syncthreads();
    kt += 64;
  }

  // epilogue: D mapping col = lane&15, row = (lane>>4)*4 + r  [m89-verified]
  #pragma unroll
  for (int j = 0; j < 4; ++j) {
    const long gc = bn + wn * 64 + j * 16 + (lane & 15);
    const float addv = (EPI == 1) ? Padd[(bm >> 7) * (long)N + gc] : bias[gc];
    #pragma unroll
    for (int i = 0; i < 4; ++i) {
      const long gr0 = bm + wm * 64 + i * 16 + ((lane >> 4) << 2);
      #pragma unroll
      for (int r = 0; r < 4; ++r)
        outf[(gr0 + r) * (long)N + gc] = acc[i][j][r] + addv;
    }
  }
}

// ------------- exclusive scan over 32 chunks per (b, o); writes v (f32) -------------
__global__ void scan_chunks(const float* __restrict__ partials, bf16_t* __restrict__ prefixb,
                            float* __restrict__ v_out) {
  const int idx = blockIdx.x * blockDim.x + threadIdx.x;  // 0..4095
  const int b = idx >> 9;
  const int o = idx & 511;
  float run = 0.f;
  #pragma unroll
  for (int c = 0; c < 32; ++c) {
    const size_t off = ((size_t)(b * 32 + c)) * 512 + o;
    prefixb[off] = (bf16_t)run;      // exclusive prefix, bf16 (feeds P-GEMM)
    run += partials[off];
  }
  v_out[idx] = run;                  // v[b][o], f32
}

extern "C" void kernel_launch(void* const* d_in, const int* in_sizes, int n_in,
                              void* d_out, int out_size, void* d_ws, size_t ws_size,
                              hipStream_t stream) {
  const float* x     = (const float*)d_in[0];   // (8,4096,1024)
  const float* mask  = (const float*)d_in[1];   // (8,4096)
  const float* W_enc = (const float*)d_in[2];   // (512,1024)
  const float* b_enc = (const float*)d_in[3];   // (512,)
  const float* W_dec = (const float*)d_in[4];   // (1024,512)
  const float* b_dec = (const float*)d_in[5];   // (1024,)

  float* out     = (float*)d_out;
  float* v_out   = out;            // 8*512
  float* out_enc = out + 4096;     // 8*4096*1024

  char* ws = (char*)d_ws;
  bf16_t* Web      = (bf16_t*)ws;  ws += (size_t)512 * 1024 * 2;    // 1 MB
  bf16_t* Wdb      = (bf16_t*)ws;  ws += (size_t)1024 * 512 * 2;    // 1 MB
  bf16_t* h        = (bf16_t*)ws;  ws += (size_t)32768 * 512 * 2;   // 33.5 MB (cumulated, bf16)
  float*  partials = (float*)ws;   ws += (size_t)256 * 512 * 4;     // 512 KB
  bf16_t* prefixb  = (bf16_t*)ws;  ws += (size_t)256 * 512 * 2;     // 256 KB
  float*  P        = (float*)ws;   ws += (size_t)256 * 1024 * 4;    // 1 MB

  // 1) cast both weight matrices (each 512*1024 f32 -> 131072 f32x4)
  cast_weights<<<1024, 256, 0, stream>>>(W_enc, Web, W_dec, Wdb, 131072);

  // 2) GEMM1 fused: h = cumsum_128(relu(x @ W_enc^T + b_enc) * mask), partials
  gemm1_fused<<<dim3(256, 4), 256, 0, stream>>>(x, Web, b_enc, mask, h, partials);

  // 3) scan chunk sums -> exclusive prefixes (bf16) and v (f32, output 0)
  scan_chunks<<<16, 256, 0, stream>>>(partials, prefixb, v_out);

  // 4) P[r,d] = prefix[r,:] @ W_dec[d,:] + b_dec[d]   [M=256, N=1024, K=512]
  gemm_bt<2><<<dim3(2, 8), 256, 0, stream>>>(prefixb, Wdb, 512, 1024, b_dec, nullptr, P);

  // 5) GEMM2: out_enc = h_local @ W_dec^T + P[chunk]  [M=32768, N=1024, K=512]
  gemm_bt<1><<<dim3(256, 8), 256, 0, stream>>>(h, Wdb, 512, 1024, nullptr, P, out_enc);
}

// Round 3
// 163.735 us; speedup vs baseline: 1.2759x; 1.0092x over previous
//
#include <hip/hip_runtime.h>
#include <hip/hip_bf16.h>
#include <stdint.h>

typedef __bf16 bf16_t;
typedef __bf16 bf16x4 __attribute__((ext_vector_type(4)));
typedef __bf16 bf16x8 __attribute__((ext_vector_type(8)));
typedef float  f32x4  __attribute__((ext_vector_type(4)));

// async global -> LDS, 16B per lane. LDS dest must be wave-uniform base (lanes scatter +16B each).
__device__ __forceinline__ void gload_lds16(const void* g, void* l) {
  __builtin_amdgcn_global_load_lds(
      (__attribute__((address_space(1))) void*)g,
      (__attribute__((address_space(3))) void*)l, 16, 0, 0);
}

// ---------------- f32 -> bf16 cast, 4 elems/thread, grid-stride ----------------
__global__ void cast_kernel(const float* __restrict__ in, bf16_t* __restrict__ out, int n4) {
  const int stride = gridDim.x * blockDim.x;
  for (int i = blockIdx.x * blockDim.x + threadIdx.x; i < n4; i += stride) {
    f32x4 v = reinterpret_cast<const f32x4*>(in)[i];
    bf16x4 o;
    o[0] = (bf16_t)v[0]; o[1] = (bf16_t)v[1]; o[2] = (bf16_t)v[2]; o[3] = (bf16_t)v[3];
    reinterpret_cast<bf16x4*>(out)[i] = o;
  }
}

// ---------------- weights cast: W_enc and W_dec in one launch ----------------
__global__ void cast_weights(const float* __restrict__ a, bf16_t* __restrict__ oa,
                             const float* __restrict__ b, bf16_t* __restrict__ ob,
                             int n4each) {
  const int i = blockIdx.x * blockDim.x + threadIdx.x;
  const float* src; bf16_t* dst; int k;
  if (i < n4each) { src = a; dst = oa; k = i; }
  else            { src = b; dst = ob; k = i - n4each; }
  f32x4 v = reinterpret_cast<const f32x4*>(src)[k];
  bf16x4 o;
  o[0] = (bf16_t)v[0]; o[1] = (bf16_t)v[1]; o[2] = (bf16_t)v[2]; o[3] = (bf16_t)v[3];
  reinterpret_cast<bf16x4*>(dst)[k] = o;
}

// ======================= 256x256 8-phase GEMM template =======================
// C[m,n] = sum_k A[m,k]*B[n,k], A: MxK row-major bf16, B: NxK row-major bf16.
// 512 threads = 8 waves (2M x 4N), per-wave out 128x64, BK=64, 128KB LDS 2-dbuf.
// Phases per K-tile: (rh,ch) = (0,0),(0,1),(1,0),(1,1); 16 MFMA each.
// Staging during tile t: p0: t+1.B1h | p1: t+2.A0h | p2: t+2.B0h | p3: t+2.A1h
//   (each region's last ds_read phase is >=1 barrier before its stage issue).
// vmcnt(6) once per K-tile boundary (3 half-tiles = 6 loads/wave in flight).
// EPI 0: fused h-epilogue: relu(acc+bias)*mask -> LDS bf16 tile -> 128-row column
//        cumsum -> h (bf16, N=512) + per-chunk partials (f32).
// EPI 1: outf[m,n] = acc + Padd[chunk(m)][n]  (GEMM2, N=1024)

#define PHASE_SYNC() do { \
  __builtin_amdgcn_s_barrier(); \
  asm volatile("s_waitcnt lgkmcnt(0)" ::: "memory"); \
  __builtin_amdgcn_sched_barrier(0); \
  __builtin_amdgcn_s_setprio(1); \
} while (0)

#define PHASE_END() do { \
  __builtin_amdgcn_s_setprio(0); \
  __builtin_amdgcn_s_barrier(); \
} while (0)

#define QUAD(RH, CH, BF) do { \
  _Pragma("unroll") \
  for (int fr = 0; fr < 4; ++fr) { \
    _Pragma("unroll") \
    for (int fc = 0; fc < 2; ++fc) { \
      acc[RH][CH][fr][fc] = __builtin_amdgcn_mfma_f32_16x16x32_bf16(a[fr][0], BF[fc][0], acc[RH][CH][fr][fc], 0, 0, 0); \
      acc[RH][CH][fr][fc] = __builtin_amdgcn_mfma_f32_16x16x32_bf16(a[fr][1], BF[fc][1], acc[RH][CH][fr][fc], 0, 0, 0); \
    } \
  } \
} while (0)

template<int EPI>
__global__ __launch_bounds__(512, 2) void gemm8p(
    const bf16_t* __restrict__ A, const bf16_t* __restrict__ B,
    const int K, const int N,
    const float* __restrict__ bias, const float* __restrict__ mask,
    const float* __restrict__ Padd,
    bf16_t* __restrict__ h_out, float* __restrict__ partials,
    float* __restrict__ outf)
{
  __shared__ __align__(16) char smem[131072];  // 2 bufs x (A 256x64 + B 256x64) bf16

  const int tid  = threadIdx.x;
  const int lane = tid & 63;
  const int w    = tid >> 6;        // 0..7
  const int wm   = w >> 2;          // 0..1
  const int wn   = w & 3;           // 0..3
  const long bm  = (long)blockIdx.x * 256;
  const long bn  = (long)blockIdx.y * 256;
  const int NT   = K >> 6;          // K-tiles (assumed >= 4)

  // staging source col pre-swizzle (involution of read swizzle): colblk ^= rowlocal&7
  const int scol = (((lane & 7) ^ (lane >> 3)) << 3);
  // frag read col offsets (elements), swizzled: (rowlocal&7) == (lane&7)
  const int fcb0 = ((((lane >> 4)    ) ^ (lane & 7)) << 3);
  const int fcb1 = ((((lane >> 4) + 4) ^ (lane & 7)) << 3);

  f32x4  acc[2][2][4][2] = {};
  bf16x8 a[4][2], b0[2][2], b1[2][2];

  auto Albs = [&](int buf) { return (bf16_t*)(smem + buf * 65536); };
  auto Blbs = [&](int buf) { return (bf16_t*)(smem + buf * 65536 + 32768); };

  auto stageA = [&](int t, int h) {
    bf16_t* lb = Albs(t & 1);
    #pragma unroll
    for (int c = 0; c < 2; ++c) {
      const int r0 = h * 128 + (w * 2 + c) * 8;
      gload_lds16(A + (bm + r0 + (lane >> 3)) * (long)K + t * 64 + scol, lb + r0 * 64);
    }
  };
  auto stageB = [&](int t, int h) {
    bf16_t* lb = Blbs(t & 1);
    #pragma unroll
    for (int c = 0; c < 2; ++c) {
      const int r0 = h * 128 + (w * 2 + c) * 8;
      gload_lds16(B + (bn + r0 + (lane >> 3)) * (long)K + t * 64 + scol, lb + r0 * 64);
    }
  };
  auto loadA = [&](int buf, int rh) {
    const bf16_t* lb = Albs(buf);
    #pragma unroll
    for (int fr = 0; fr < 4; ++fr) {
      const int row = rh * 128 + wm * 64 + fr * 16 + (lane & 15);
      a[fr][0] = *reinterpret_cast<const bf16x8*>(lb + row * 64 + fcb0);
      a[fr][1] = *reinterpret_cast<const bf16x8*>(lb + row * 64 + fcb1);
    }
  };
  auto loadB = [&](int buf, int ch, bf16x8 (&bf)[2][2]) {
    const bf16_t* lb = Blbs(buf);
    #pragma unroll
    for (int fc = 0; fc < 2; ++fc) {
      const int row = ch * 128 + wn * 32 + fc * 16 + (lane & 15);
      bf[fc][0] = *reinterpret_cast<const bf16x8*>(lb + row * 64 + fcb0);
      bf[fc][1] = *reinterpret_cast<const bf16x8*>(lb + row * 64 + fcb1);
    }
  };

  // ---- prologue: tile0 fully + tile1 {A0,B0,A1}; per-wave 14 loads -> vmcnt(6) ----
  __builtin_amdgcn_sched_barrier(0);
  stageA(0, 0); stageA(0, 1); stageB(0, 0); stageB(0, 1);
  stageA(1, 0); stageB(1, 0); stageA(1, 1);
  asm volatile("s_waitcnt vmcnt(6)" ::: "memory");
  __builtin_amdgcn_s_barrier();

  for (int t = 0; t < NT; ++t) {
    const int buf = t & 1;
    const bool s2 = (t + 2 < NT);
    const bool s1 = (t + 1 < NT);

    // p0: reads A-h0 + B-h0 of tile t
    loadA(buf, 0);
    loadB(buf, 0, b0);
    if (s1) stageB(t + 1, 1);
    PHASE_SYNC(); QUAD(0, 0, b0); PHASE_END();

    // p1: reads B-h1
    loadB(buf, 1, b1);
    if (s2) stageA(t + 2, 0);
    PHASE_SYNC(); QUAD(0, 1, b1); PHASE_END();

    // p2: reads A-h1
    loadA(buf, 1);
    if (s2) stageB(t + 2, 0);
    PHASE_SYNC(); QUAD(1, 0, b0); PHASE_END();

    // p3: no ds reads
    if (s2) stageA(t + 2, 1);
    PHASE_SYNC(); QUAD(1, 1, b1);
    __builtin_amdgcn_s_setprio(0);
    if (s2)      { asm volatile("s_waitcnt vmcnt(6)" ::: "memory"); }
    else if (s1) { asm volatile("s_waitcnt vmcnt(0)" ::: "memory"); }
    __builtin_amdgcn_s_barrier();
  }
  __builtin_amdgcn_sched_barrier(0);

  if (EPI == 0) {
    // ---- fused epilogue: relu+bias+mask -> swizzled bf16 LDS tile ----
    bf16_t* tile = (bf16_t*)smem;  // [256][256] bf16, col ^ ((row>>2)&3)<<4
    float bv[2][2];
    #pragma unroll
    for (int ch = 0; ch < 2; ++ch)
      #pragma unroll
      for (int fc = 0; fc < 2; ++fc)
        bv[ch][fc] = bias[bn + ch * 128 + wn * 32 + fc * 16 + (lane & 15)];

    #pragma unroll
    for (int rh = 0; rh < 2; ++rh)
      #pragma unroll
      for (int fr = 0; fr < 4; ++fr) {
        const int row0 = rh * 128 + wm * 64 + fr * 16 + ((lane >> 4) << 2);
        const f32x4 mv = *reinterpret_cast<const f32x4*>(&mask[bm + row0]);
        #pragma unroll
        for (int ch = 0; ch < 2; ++ch)
          #pragma unroll
          for (int fc = 0; fc < 2; ++fc) {
            const int col = ch * 128 + wn * 32 + fc * 16 + (lane & 15);
            #pragma unroll
            for (int e = 0; e < 4; ++e) {
              const int row = row0 + e;
              float hv = acc[rh][ch][fr][fc][e] + bv[ch][fc];
              hv = (hv > 0.f ? hv : 0.f) * mv[e];
              tile[row * 256 + (col ^ (((row >> 2) & 3) << 4))] = (bf16_t)hv;
            }
          }
      }
    __syncthreads();

    // ---- column cumsum over each 128-row chunk (2 chunks per block, 512 threads) ----
    const int sub = tid >> 8;          // chunk half 0/1
    const int col = tid & 255;
    float run = 0.f;
    bf16_t* hp = h_out + (bm + sub * 128) * 512 + bn + col;
    #pragma unroll 4
    for (int s = 0; s < 128; ++s) {
      const int row = sub * 128 + s;
      run += (float)tile[row * 256 + (col ^ (((row >> 2) & 3) << 4))];
      hp[(long)s * 512] = (bf16_t)run;
    }
    partials[(blockIdx.x * 2 + sub) * 512 + bn + col] = run;
  } else {
    // ---- GEMM2 epilogue: + per-chunk P, f32 stores ----
    #pragma unroll
    for (int rh = 0; rh < 2; ++rh)
      #pragma unroll
      for (int ch = 0; ch < 2; ++ch)
        #pragma unroll
        for (int fc = 0; fc < 2; ++fc) {
          const long gc = bn + ch * 128 + wn * 32 + fc * 16 + (lane & 15);
          const float pv = Padd[(blockIdx.x * 2 + rh) * (long)N + gc];
          #pragma unroll
          for (int fr = 0; fr < 4; ++fr) {
            const long gr = bm + rh * 128 + wm * 64 + fr * 16 + ((lane >> 4) << 2);
            #pragma unroll
            for (int e = 0; e < 4; ++e)
              outf[(gr + e) * (long)N + gc] = acc[rh][ch][fr][fc][e] + pv;
          }
        }
  }
}

// ================= small B^T GEMM for P (128x128 tile, dbuf) ==================
__global__ __launch_bounds__(256) void gemm_p(
    const bf16_t* __restrict__ A, const bf16_t* __restrict__ B,
    const int K, const int N,
    const float* __restrict__ bias,
    float* __restrict__ outf)
{
  __shared__ __align__(16) bf16_t As[2][128 * 64];
  __shared__ __align__(16) bf16_t Bs[2][128 * 64];

  const int tid  = threadIdx.x;
  const int lane = tid & 63;
  const int w    = tid >> 6;
  const int wm   = w >> 1, wn = w & 1;
  const long bm  = (long)blockIdx.x * 128;
  const long bn  = (long)blockIdx.y * 128;

  f32x4 acc[4][4] = {};

  const int srow = w * 32 + (lane >> 3);
  const int scol = (lane & 7) * 8;
  const bf16_t* Abase = A + (bm + srow) * (long)K + scol;
  const bf16_t* Bbase = B + (bn + srow) * (long)K + scol;

  auto stage = [&](bf16_t* da, bf16_t* db, int kt) {
    #pragma unroll
    for (int it = 0; it < 4; ++it) {
      gload_lds16(Abase + (long)it * 8 * K + kt, &da[(w * 32 + it * 8) * 64]);
      gload_lds16(Bbase + (long)it * 8 * K + kt, &db[(w * 32 + it * 8) * 64]);
    }
  };
  auto mfma_tile = [&](const bf16_t* Asb, const bf16_t* Bsb) {
    #pragma unroll
    for (int kk = 0; kk < 2; ++kk) {
      const int kof = kk * 32 + (lane >> 4) * 8;
      bf16x8 afr[4], bfr[4];
      #pragma unroll
      for (int i = 0; i < 4; ++i)
        afr[i] = *reinterpret_cast<const bf16x8*>(&Asb[(wm * 64 + i * 16 + (lane & 15)) * 64 + kof]);
      #pragma unroll
      for (int j = 0; j < 4; ++j)
        bfr[j] = *reinterpret_cast<const bf16x8*>(&Bsb[(wn * 64 + j * 16 + (lane & 15)) * 64 + kof]);
      #pragma unroll
      for (int i = 0; i < 4; ++i)
        #pragma unroll
        for (int j = 0; j < 4; ++j)
          acc[i][j] = __builtin_amdgcn_mfma_f32_16x16x32_bf16(afr[i], bfr[j], acc[i][j], 0, 0, 0);
    }
  };

  stage(As[0], Bs[0], 0);
  __syncthreads();
  int kt = 64;
  for (int p2 = 0; p2 < (K >> 7); ++p2) {
    if (kt < K) stage(As[1], Bs[1], kt);
    mfma_tile(As[0], Bs[0]);
    __syncthreads();
    kt += 64;
    if (kt < K) stage(As[0], Bs[0], kt);
    mfma_tile(As[1], Bs[1]);
    __syncthreads();
    kt += 64;
  }

  #pragma unroll
  for (int j = 0; j < 4; ++j) {
    const long gc = bn + wn * 64 + j * 16 + (lane & 15);
    const float addv = bias[gc];
    #pragma unroll
    for (int i = 0; i < 4; ++i) {
      const long gr0 = bm + wm * 64 + i * 16 + ((lane >> 4) << 2);
      #pragma unroll
      for (int r = 0; r < 4; ++r)
        outf[(gr0 + r) * (long)N + gc] = acc[i][j][r] + addv;
    }
  }
}

// ------------- exclusive scan over 32 chunks per (b, o); writes v (f32) -------------
__global__ void scan_chunks(const float* __restrict__ partials, bf16_t* __restrict__ prefixb,
                            float* __restrict__ v_out) {
  const int idx = blockIdx.x * blockDim.x + threadIdx.x;  // 0..4095
  const int b = idx >> 9;
  const int o = idx & 511;
  float run = 0.f;
  #pragma unroll
  for (int c = 0; c < 32; ++c) {
    const size_t off = ((size_t)(b * 32 + c)) * 512 + o;
    prefixb[off] = (bf16_t)run;      // exclusive prefix, bf16 (feeds P-GEMM)
    run += partials[off];
  }
  v_out[idx] = run;                  // v[b][o], f32
}

extern "C" void kernel_launch(void* const* d_in, const int* in_sizes, int n_in,
                              void* d_out, int out_size, void* d_ws, size_t ws_size,
                              hipStream_t stream) {
  const float* x     = (const float*)d_in[0];   // (8,4096,1024)
  const float* mask  = (const float*)d_in[1];   // (8,4096)
  const float* W_enc = (const float*)d_in[2];   // (512,1024)
  const float* b_enc = (const float*)d_in[3];   // (512,)
  const float* W_dec = (const float*)d_in[4];   // (1024,512)
  const float* b_dec = (const float*)d_in[5];   // (1024,)

  float* out     = (float*)d_out;
  float* v_out   = out;            // 8*512
  float* out_enc = out + 4096;     // 8*4096*1024

  char* ws = (char*)d_ws;
  bf16_t* xb       = (bf16_t*)ws;  ws += (size_t)32768 * 1024 * 2;  // 67 MB
  bf16_t* Web      = (bf16_t*)ws;  ws += (size_t)512 * 1024 * 2;    // 1 MB
  bf16_t* Wdb      = (bf16_t*)ws;  ws += (size_t)1024 * 512 * 2;    // 1 MB
  bf16_t* h        = (bf16_t*)ws;  ws += (size_t)32768 * 512 * 2;   // 33.5 MB (cumulated)
  float*  partials = (float*)ws;   ws += (size_t)256 * 512 * 4;     // 512 KB
  bf16_t* prefixb  = (bf16_t*)ws;  ws += (size_t)256 * 512 * 2;     // 256 KB
  float*  P        = (float*)ws;   ws += (size_t)256 * 1024 * 4;    // 1 MB

  // 1) casts
  cast_kernel<<<2048, 256, 0, stream>>>(x, xb, 33554432 / 4);
  cast_weights<<<1024, 256, 0, stream>>>(W_enc, Web, W_dec, Wdb, 131072);

  // 2) GEMM1 (8-phase 256^2) fused with chunk-local cumsum:
  //    h = cumsum_128(relu(x @ W_enc^T + b_enc) * mask), partials per chunk
  gemm8p<0><<<dim3(128, 2), 512, 0, stream>>>(xb, Web, 1024, 512,
                                              b_enc, mask, nullptr, h, partials, nullptr);

  // 3) scan chunk sums -> exclusive prefixes (bf16) and v (f32, output 0)
  scan_chunks<<<16, 256, 0, stream>>>(partials, prefixb, v_out);

  // 4) P[r,d] = prefix[r,:] @ W_dec[d,:] + b_dec[d]   [M=256, N=1024, K=512]
  gemm_p<<<dim3(2, 8), 256, 0, stream>>>(prefixb, Wdb, 512, 1024, b_dec, P);

  // 5) GEMM2 (8-phase 256^2): out_enc = h_local @ W_dec^T + P[chunk]
  gemm8p<1><<<dim3(128, 4), 512, 0, stream>>>(h, Wdb, 512, 1024,
                                              nullptr, nullptr, P, nullptr, nullptr, out_enc);
}

// Round 4
// 138.872 us; speedup vs baseline: 1.5044x; 1.1790x over previous
//
#include <hip/hip_runtime.h>
#include <hip/hip_bf16.h>
#include <stdint.h>

typedef __bf16 bf16_t;
typedef __bf16 bf16x4 __attribute__((ext_vector_type(4)));
typedef __bf16 bf16x8 __attribute__((ext_vector_type(8)));
typedef float  f32x4  __attribute__((ext_vector_type(4)));

// async global -> LDS, 16B per lane. LDS dest must be wave-uniform base (lanes scatter +16B each).
__device__ __forceinline__ void gload_lds16(const void* g, void* l) {
  __builtin_amdgcn_global_load_lds(
      (__attribute__((address_space(1))) void*)g,
      (__attribute__((address_space(3))) void*)l, 16, 0, 0);
}

// ---------------- weights cast: W_enc and W_dec in one launch ----------------
__global__ void cast_weights(const float* __restrict__ a, bf16_t* __restrict__ oa,
                             const float* __restrict__ b, bf16_t* __restrict__ ob,
                             int n4each) {
  const int i = blockIdx.x * blockDim.x + threadIdx.x;
  const float* src; bf16_t* dst; int k;
  if (i < n4each) { src = a; dst = oa; k = i; }
  else            { src = b; dst = ob; k = i - n4each; }
  f32x4 v = reinterpret_cast<const f32x4*>(src)[k];
  bf16x4 o;
  o[0] = (bf16_t)v[0]; o[1] = (bf16_t)v[1]; o[2] = (bf16_t)v[2]; o[3] = (bf16_t)v[3];
  reinterpret_cast<bf16x4*>(dst)[k] = o;
}

#define PHASE_SYNC() do { \
  __builtin_amdgcn_s_barrier(); \
  asm volatile("s_waitcnt lgkmcnt(0)" ::: "memory"); \
  __builtin_amdgcn_sched_barrier(0); \
  __builtin_amdgcn_s_setprio(1); \
} while (0)

#define PHASE_END() do { \
  __builtin_amdgcn_s_setprio(0); \
  __builtin_amdgcn_s_barrier(); \
} while (0)

#define QUAD(RH, CH, BF) do { \
  _Pragma("unroll") \
  for (int fr = 0; fr < 4; ++fr) { \
    _Pragma("unroll") \
    for (int fc = 0; fc < 2; ++fc) { \
      acc[RH][CH][fr][fc] = __builtin_amdgcn_mfma_f32_16x16x32_bf16(a[fr][0], BF[fc][0], acc[RH][CH][fr][fc], 0, 0, 0); \
      acc[RH][CH][fr][fc] = __builtin_amdgcn_mfma_f32_16x16x32_bf16(a[fr][1], BF[fc][1], acc[RH][CH][fr][fc], 0, 0, 0); \
    } \
  } \
} while (0)

// ============ GEMM1 fused (cast + relu/bias/mask + chunk cumsum), 256x256 8-phase ============
// A = x (f32!) staged via gload_lds into single-buffered f32 LDS; B = W_enc bf16 dbuf.
// M=32768 grid.x=128, N=512 grid.y=2, K=1024 (NT=16).
__global__ __launch_bounds__(512, 2) void gemm1_f8p(
    const float* __restrict__ x, const bf16_t* __restrict__ Wenc,
    const float* __restrict__ b_enc, const float* __restrict__ mask,
    bf16_t* __restrict__ h_out, float* __restrict__ partials)
{
  __shared__ __align__(16) char smem[131072];
  float* Af = (float*)smem;  // 256x64 f32, single buffer (halves ping-pong)
  auto Bl = [&](int buf) { return (bf16_t*)(smem + 65536 + buf * 32768); };

  const int tid  = threadIdx.x;
  const int lane = tid & 63;
  const int w    = tid >> 6;
  const int wm   = w >> 2;
  const int wn   = w & 3;
  const long bm  = (long)blockIdx.x * 256;
  const long bn  = (long)blockIdx.y * 256;
  const int NT   = 16;

  f32x4  acc[2][2][4][2] = {};
  bf16x8 a[4][2], b0[2][2], b1[2][2];

  // B staging (bf16, 3-bit XOR pre-swizzle on source)
  const int scolB = (((lane & 7) ^ (lane >> 3)) << 3);
  auto stageB = [&](int t, int h) {
    bf16_t* lb = Bl(t & 1);
    #pragma unroll
    for (int c = 0; c < 2; ++c) {
      const int r0 = h * 128 + (w * 2 + c) * 8;
      gload_lds16(Wenc + (bn + r0 + (lane >> 3)) * 1024 + t * 64 + scolB, lb + r0 * 64);
    }
  };
  // A staging (f32, 4-bit XOR pre-swizzle key = row&15)
  auto stageA = [&](int t, int h) {
    #pragma unroll
    for (int c = 0; c < 4; ++c) {
      const int r0  = h * 128 + w * 16 + c * 4;
      const int row = r0 + (lane >> 4);
      const int sblk = (lane & 15) ^ (row & 15);
      gload_lds16(x + (bm + row) * 1024 + t * 64 + sblk * 4, Af + r0 * 64);
    }
  };
  auto loadAf = [&](int rh) {
    #pragma unroll
    for (int fr = 0; fr < 4; ++fr) {
      const int row = rh * 128 + wm * 64 + fr * 16 + (lane & 15);
      const float* rp = Af + row * 64;
      #pragma unroll
      for (int kx = 0; kx < 2; ++kx) {
        const int g0 = kx * 8 + (lane >> 4) * 2;
        f32x4 lo = *reinterpret_cast<const f32x4*>(rp + (((g0    ) ^ (lane & 15)) << 2));
        f32x4 hi = *reinterpret_cast<const f32x4*>(rp + (((g0 + 1) ^ (lane & 15)) << 2));
        bf16x8 o;
        #pragma unroll
        for (int e = 0; e < 4; ++e) { o[e] = (bf16_t)lo[e]; o[e + 4] = (bf16_t)hi[e]; }
        a[fr][kx] = o;
      }
    }
  };
  const int fcb0 = ((((lane >> 4)    ) ^ (lane & 7)) << 3);
  const int fcb1 = ((((lane >> 4) + 4) ^ (lane & 7)) << 3);
  auto loadB = [&](int buf, int ch, bf16x8 (&bf)[2][2]) {
    const bf16_t* lb = Bl(buf);
    #pragma unroll
    for (int fc = 0; fc < 2; ++fc) {
      const int row = ch * 128 + wn * 32 + fc * 16 + (lane & 15);
      bf[fc][0] = *reinterpret_cast<const bf16x8*>(lb + row * 64 + fcb0);
      bf[fc][1] = *reinterpret_cast<const bf16x8*>(lb + row * 64 + fcb1);
    }
  };

  // prologue: tile0 A+B (12 loads/wave) then B(1,*) (4) -> vmcnt(4)
  __builtin_amdgcn_sched_barrier(0);
  stageA(0, 0); stageA(0, 1); stageB(0, 0); stageB(0, 1);
  stageB(1, 0); stageB(1, 1);
  asm volatile("s_waitcnt vmcnt(4)" ::: "memory");
  __builtin_amdgcn_s_barrier();

  for (int t = 0; t < NT; ++t) {
    const int buf = t & 1;
    const bool g1 = (t + 1 < NT);
    const bool g2 = (t + 2 < NT);

    // p0: reads A-h0(f32) + B-h0
    loadAf(0); loadB(buf, 0, b0);
    PHASE_SYNC(); QUAD(0, 0, b0); PHASE_END();

    // p1: reads B-h1; stage A(t+1,0) [region freed after p0], B(t+2,0)
    loadB(buf, 1, b1);
    if (g1) stageA(t + 1, 0);
    if (g2) stageB(t + 2, 0);
    PHASE_SYNC(); QUAD(0, 1, b1);
    __builtin_amdgcn_s_setprio(0);
    // publish A(t,1) for p2 readers (cross-wave: wait BEFORE barrier)
    if (g2)      asm volatile("s_waitcnt vmcnt(6)" ::: "memory");
    else if (g1) asm volatile("s_waitcnt vmcnt(4)" ::: "memory");
    else         asm volatile("s_waitcnt vmcnt(0)" ::: "memory");
    __builtin_amdgcn_s_barrier();

    // p2: reads A-h1(f32); stage B(t+2,1)
    loadAf(1);
    if (g2) stageB(t + 2, 1);
    PHASE_SYNC(); QUAD(1, 0, b0); PHASE_END();

    // p3: stage A(t+1,1) [region freed after p2]
    if (g1) stageA(t + 1, 1);
    PHASE_SYNC(); QUAD(1, 1, b1);
    __builtin_amdgcn_s_setprio(0);
    if (g2)      asm volatile("s_waitcnt vmcnt(8)" ::: "memory");
    else if (g1) asm volatile("s_waitcnt vmcnt(4)" ::: "memory");
    else         asm volatile("s_waitcnt vmcnt(0)" ::: "memory");
    __builtin_amdgcn_s_barrier();
  }
  asm volatile("s_waitcnt vmcnt(0) lgkmcnt(0)" ::: "memory");
  __builtin_amdgcn_s_barrier();
  __builtin_amdgcn_sched_barrier(0);

  // ---- fused epilogue: relu+bias+mask -> swizzled bf16 LDS tile ----
  bf16_t* tile = (bf16_t*)smem;  // [256][256] bf16, col ^ ((row>>2)&3)<<4
  float bv[2][2];
  #pragma unroll
  for (int ch = 0; ch < 2; ++ch)
    #pragma unroll
    for (int fc = 0; fc < 2; ++fc)
      bv[ch][fc] = b_enc[bn + ch * 128 + wn * 32 + fc * 16 + (lane & 15)];

  #pragma unroll
  for (int rh = 0; rh < 2; ++rh)
    #pragma unroll
    for (int fr = 0; fr < 4; ++fr) {
      const int row0 = rh * 128 + wm * 64 + fr * 16 + ((lane >> 4) << 2);
      const f32x4 mv = *reinterpret_cast<const f32x4*>(&mask[bm + row0]);
      #pragma unroll
      for (int ch = 0; ch < 2; ++ch)
        #pragma unroll
        for (int fc = 0; fc < 2; ++fc) {
          const int col = ch * 128 + wn * 32 + fc * 16 + (lane & 15);
          #pragma unroll
          for (int e = 0; e < 4; ++e) {
            const int row = row0 + e;
            float hv = acc[rh][ch][fr][fc][e] + bv[ch][fc];
            hv = (hv > 0.f ? hv : 0.f) * mv[e];
            tile[row * 256 + (col ^ (((row >> 2) & 3) << 4))] = (bf16_t)hv;
          }
        }
    }
  __syncthreads();

  // ---- column cumsum over each 128-row chunk (2 chunks per block) ----
  const int sub = tid >> 8;
  const int col = tid & 255;
  float run = 0.f;
  bf16_t* hp = h_out + (bm + sub * 128) * 512 + bn + col;
  #pragma unroll 4
  for (int s = 0; s < 128; ++s) {
    const int row = sub * 128 + s;
    run += (float)tile[row * 256 + (col ^ (((row >> 2) & 3) << 4))];
    hp[(long)s * 512] = (bf16_t)run;
  }
  partials[(blockIdx.x * 2 + sub) * 512 + bn + col] = run;
}

// ============ GEMM2: out_enc = h @ W_dec^T + P[chunk], 256x256 8-phase, deep staging ============
__global__ __launch_bounds__(512, 2) void gemm2_8p(
    const bf16_t* __restrict__ A, const bf16_t* __restrict__ B,
    const int K, const int N,
    const float* __restrict__ Padd,
    float* __restrict__ outf)
{
  __shared__ __align__(16) char smem[131072];

  const int tid  = threadIdx.x;
  const int lane = tid & 63;
  const int w    = tid >> 6;
  const int wm   = w >> 2;
  const int wn   = w & 3;
  const long bm  = (long)blockIdx.x * 256;
  const long bn  = (long)blockIdx.y * 256;
  const int NT   = K >> 6;

  const int scol = (((lane & 7) ^ (lane >> 3)) << 3);
  const int fcb0 = ((((lane >> 4)    ) ^ (lane & 7)) << 3);
  const int fcb1 = ((((lane >> 4) + 4) ^ (lane & 7)) << 3);

  f32x4  acc[2][2][4][2] = {};
  bf16x8 a[4][2], b0[2][2], b1[2][2];

  auto Albs = [&](int buf) { return (bf16_t*)(smem + buf * 65536); };
  auto Blbs = [&](int buf) { return (bf16_t*)(smem + buf * 65536 + 32768); };

  auto stageA = [&](int t, int h) {
    bf16_t* lb = Albs(t & 1);
    #pragma unroll
    for (int c = 0; c < 2; ++c) {
      const int r0 = h * 128 + (w * 2 + c) * 8;
      gload_lds16(A + (bm + r0 + (lane >> 3)) * (long)K + t * 64 + scol, lb + r0 * 64);
    }
  };
  auto stageB = [&](int t, int h) {
    bf16_t* lb = Blbs(t & 1);
    #pragma unroll
    for (int c = 0; c < 2; ++c) {
      const int r0 = h * 128 + (w * 2 + c) * 8;
      gload_lds16(B + (bn + r0 + (lane >> 3)) * (long)K + t * 64 + scol, lb + r0 * 64);
    }
  };
  auto loadA = [&](int buf, int rh) {
    const bf16_t* lb = Albs(buf);
    #pragma unroll
    for (int fr = 0; fr < 4; ++fr) {
      const int row = rh * 128 + wm * 64 + fr * 16 + (lane & 15);
      a[fr][0] = *reinterpret_cast<const bf16x8*>(lb + row * 64 + fcb0);
      a[fr][1] = *reinterpret_cast<const bf16x8*>(lb + row * 64 + fcb1);
    }
  };
  auto loadB = [&](int buf, int ch, bf16x8 (&bf)[2][2]) {
    const bf16_t* lb = Blbs(buf);
    #pragma unroll
    for (int fc = 0; fc < 2; ++fc) {
      const int row = ch * 128 + wn * 32 + fc * 16 + (lane & 15);
      bf[fc][0] = *reinterpret_cast<const bf16x8*>(lb + row * 64 + fcb0);
      bf[fc][1] = *reinterpret_cast<const bf16x8*>(lb + row * 64 + fcb1);
    }
  };

  // prologue: tile0 (8 loads/wave) + tile1 (8) -> vmcnt(8)
  __builtin_amdgcn_sched_barrier(0);
  stageA(0, 0); stageA(0, 1); stageB(0, 0); stageB(0, 1);
  stageA(1, 0); stageA(1, 1); stageB(1, 0); stageB(1, 1);
  asm volatile("s_waitcnt vmcnt(8)" ::: "memory");
  __builtin_amdgcn_s_barrier();

  for (int t = 0; t < NT; ++t) {
    const int buf = t & 1;
    const bool g2 = (t + 2 < NT);

    loadA(buf, 0); loadB(buf, 0, b0);
    PHASE_SYNC(); QUAD(0, 0, b0); PHASE_END();

    loadB(buf, 1, b1);
    if (g2) stageA(t + 2, 0);
    PHASE_SYNC(); QUAD(0, 1, b1); PHASE_END();

    loadA(buf, 1);
    if (g2) stageB(t + 2, 0);
    PHASE_SYNC(); QUAD(1, 0, b0); PHASE_END();

    if (g2) { stageA(t + 2, 1); stageB(t + 2, 1); }
    PHASE_SYNC(); QUAD(1, 1, b1);
    __builtin_amdgcn_s_setprio(0);
    if (g2) asm volatile("s_waitcnt vmcnt(8)" ::: "memory");
    else    asm volatile("s_waitcnt vmcnt(0)" ::: "memory");
    __builtin_amdgcn_s_barrier();
  }
  __builtin_amdgcn_sched_barrier(0);

  // epilogue: + per-chunk P, f32 stores (D map: col=lane&15, row=(lane>>4)*4+e)
  #pragma unroll
  for (int rh = 0; rh < 2; ++rh)
    #pragma unroll
    for (int ch = 0; ch < 2; ++ch)
      #pragma unroll
      for (int fc = 0; fc < 2; ++fc) {
        const long gc = bn + ch * 128 + wn * 32 + fc * 16 + (lane & 15);
        const float pv = Padd[(blockIdx.x * 2 + rh) * (long)N + gc];
        #pragma unroll
        for (int fr = 0; fr < 4; ++fr) {
          const long gr = bm + rh * 128 + wm * 64 + fr * 16 + ((lane >> 4) << 2);
          #pragma unroll
          for (int e = 0; e < 4; ++e)
            outf[(gr + e) * (long)N + gc] = acc[rh][ch][fr][fc][e] + pv;
        }
      }
}

// ================= small B^T GEMM for P (128x128 tile, dbuf) ==================
__global__ __launch_bounds__(256) void gemm_p(
    const bf16_t* __restrict__ A, const bf16_t* __restrict__ B,
    const int K, const int N,
    const float* __restrict__ bias,
    float* __restrict__ outf)
{
  __shared__ __align__(16) bf16_t As[2][128 * 64];
  __shared__ __align__(16) bf16_t Bs[2][128 * 64];

  const int tid  = threadIdx.x;
  const int lane = tid & 63;
  const int w    = tid >> 6;
  const int wm   = w >> 1, wn = w & 1;
  const long bm  = (long)blockIdx.x * 128;
  const long bn  = (long)blockIdx.y * 128;

  f32x4 acc[4][4] = {};

  const int srow = w * 32 + (lane >> 3);
  const int scol = (lane & 7) * 8;
  const bf16_t* Abase = A + (bm + srow) * (long)K + scol;
  const bf16_t* Bbase = B + (bn + srow) * (long)K + scol;

  auto stage = [&](bf16_t* da, bf16_t* db, int kt) {
    #pragma unroll
    for (int it = 0; it < 4; ++it) {
      gload_lds16(Abase + (long)it * 8 * K + kt, &da[(w * 32 + it * 8) * 64]);
      gload_lds16(Bbase + (long)it * 8 * K + kt, &db[(w * 32 + it * 8) * 64]);
    }
  };
  auto mfma_tile = [&](const bf16_t* Asb, const bf16_t* Bsb) {
    #pragma unroll
    for (int kk = 0; kk < 2; ++kk) {
      const int kof = kk * 32 + (lane >> 4) * 8;
      bf16x8 afr[4], bfr[4];
      #pragma unroll
      for (int i = 0; i < 4; ++i)
        afr[i] = *reinterpret_cast<const bf16x8*>(&Asb[(wm * 64 + i * 16 + (lane & 15)) * 64 + kof]);
      #pragma unroll
      for (int j = 0; j < 4; ++j)
        bfr[j] = *reinterpret_cast<const bf16x8*>(&Bsb[(wn * 64 + j * 16 + (lane & 15)) * 64 + kof]);
      #pragma unroll
      for (int i = 0; i < 4; ++i)
        #pragma unroll
        for (int j = 0; j < 4; ++j)
          acc[i][j] = __builtin_amdgcn_mfma_f32_16x16x32_bf16(afr[i], bfr[j], acc[i][j], 0, 0, 0);
    }
  };

  stage(As[0], Bs[0], 0);
  __syncthreads();
  int kt = 64;
  for (int p2 = 0; p2 < (K >> 7); ++p2) {
    if (kt < K) stage(As[1], Bs[1], kt);
    mfma_tile(As[0], Bs[0]);
    __syncthreads();
    kt += 64;
    if (kt < K) stage(As[0], Bs[0], kt);
    mfma_tile(As[1], Bs[1]);
    __syncthreads();
    kt += 64;
  }

  #pragma unroll
  for (int j = 0; j < 4; ++j) {
    const long gc = bn + wn * 64 + j * 16 + (lane & 15);
    const float addv = bias[gc];
    #pragma unroll
    for (int i = 0; i < 4; ++i) {
      const long gr0 = bm + wm * 64 + i * 16 + ((lane >> 4) << 2);
      #pragma unroll
      for (int r = 0; r < 4; ++r)
        outf[(gr0 + r) * (long)N + gc] = acc[i][j][r] + addv;
    }
  }
}

// ------------- exclusive scan over 32 chunks per (b, o); writes v (f32) -------------
__global__ void scan_chunks(const float* __restrict__ partials, bf16_t* __restrict__ prefixb,
                            float* __restrict__ v_out) {
  const int idx = blockIdx.x * blockDim.x + threadIdx.x;  // 0..4095
  const int b = idx >> 9;
  const int o = idx & 511;
  float run = 0.f;
  #pragma unroll
  for (int c = 0; c < 32; ++c) {
    const size_t off = ((size_t)(b * 32 + c)) * 512 + o;
    prefixb[off] = (bf16_t)run;
    run += partials[off];
  }
  v_out[idx] = run;
}

extern "C" void kernel_launch(void* const* d_in, const int* in_sizes, int n_in,
                              void* d_out, int out_size, void* d_ws, size_t ws_size,
                              hipStream_t stream) {
  const float* x     = (const float*)d_in[0];   // (8,4096,1024)
  const float* mask  = (const float*)d_in[1];   // (8,4096)
  const float* W_enc = (const float*)d_in[2];   // (512,1024)
  const float* b_enc = (const float*)d_in[3];   // (512,)
  const float* W_dec = (const float*)d_in[4];   // (1024,512)
  const float* b_dec = (const float*)d_in[5];   // (1024,)

  float* out     = (float*)d_out;
  float* v_out   = out;            // 8*512
  float* out_enc = out + 4096;     // 8*4096*1024

  char* ws = (char*)d_ws;
  bf16_t* Web      = (bf16_t*)ws;  ws += (size_t)512 * 1024 * 2;    // 1 MB
  bf16_t* Wdb      = (bf16_t*)ws;  ws += (size_t)1024 * 512 * 2;    // 1 MB
  bf16_t* h        = (bf16_t*)ws;  ws += (size_t)32768 * 512 * 2;   // 33.5 MB (cumulated)
  float*  partials = (float*)ws;   ws += (size_t)256 * 512 * 4;     // 512 KB
  bf16_t* prefixb  = (bf16_t*)ws;  ws += (size_t)256 * 512 * 2;     // 256 KB
  float*  P        = (float*)ws;   ws += (size_t)256 * 1024 * 4;    // 1 MB

  // 1) cast weights only (x cast is fused into GEMM1)
  cast_weights<<<1024, 256, 0, stream>>>(W_enc, Web, W_dec, Wdb, 131072);

  // 2) GEMM1 fused: h = cumsum_128(relu(x @ W_enc^T + b_enc) * mask), partials
  gemm1_f8p<<<dim3(128, 2), 512, 0, stream>>>(x, Web, b_enc, mask, h, partials);

  // 3) scan chunk sums -> exclusive prefixes (bf16) and v (f32, output 0)
  scan_chunks<<<16, 256, 0, stream>>>(partials, prefixb, v_out);

  // 4) P[r,d] = prefix[r,:] @ W_dec[d,:] + b_dec[d]   [M=256, N=1024, K=512]
  gemm_p<<<dim3(2, 8), 256, 0, stream>>>(prefixb, Wdb, 512, 1024, b_dec, P);

  // 5) GEMM2 (8-phase, deep staging): out_enc = h_local @ W_dec^T + P[chunk]
  gemm2_8p<<<dim3(128, 4), 512, 0, stream>>>(h, Wdb, 512, 1024, P, out_enc);
}